// Round 4
// baseline (270.463 us; speedup 1.0000x reference)
//
#include <hip/hip_runtime.h>

typedef __attribute__((ext_vector_type(4))) float f32x4;
typedef __attribute__((ext_vector_type(16))) float f32x16;
typedef __attribute__((ext_vector_type(8))) short bf16x8;
typedef __attribute__((ext_vector_type(4))) unsigned short u16x4;
typedef __attribute__((ext_vector_type(4))) unsigned int u32x4;

#define T_DIM 1024
#define B_DIM 8
#define E_DIM 1024
#define H_DIM 16
#define DH 64

__device__ __forceinline__ unsigned short f2bf(float f) {
  unsigned int u = __builtin_bit_cast(unsigned int, f);
  u += 0x7fffu + ((u >> 16) & 1u);   // RNE
  return (unsigned short)(u >> 16);
}

__device__ __forceinline__ unsigned int cvtpk_bf16(float lo, float hi) {
  unsigned int r;
  asm("v_cvt_pk_bf16_f32 %0, %1, %2" : "=v"(r) : "v"(lo), "v"(hi));
  return r;
}

__device__ __forceinline__ float exp2_hw(float x) {   // bare v_exp_f32 (2^x)
  float r;
  asm("v_exp_f32 %0, %1" : "=v"(r) : "v"(x));
  return r;
}

__device__ __forceinline__ f32x4 mfma16(bf16x8 a, bf16x8 b, f32x4 c) {
  return __builtin_amdgcn_mfma_f32_16x16x32_bf16(a, b, c, 0, 0, 0);
}
__device__ __forceinline__ f32x16 mfma32(bf16x8 a, bf16x8 b, f32x16 c) {
  return __builtin_amdgcn_mfma_f32_32x32x16_bf16(a, b, c, 0, 0, 0);
}

// ---------------- cast f32 -> bf16, 4 elems/thread ----------------
__global__ __launch_bounds__(256) void cast_f32_to_bf16(
    const float* __restrict__ src, unsigned short* __restrict__ dst, int n4) {
  int i = blockIdx.x * 256 + threadIdx.x;
  if (i >= n4) return;
  f32x4 v = *(const f32x4*)(src + (size_t)i * 4);
  u16x4 o;
  o[0] = f2bf(v[0]); o[1] = f2bf(v[1]); o[2] = f2bf(v[2]); o[3] = f2bf(v[3]);
  *(u16x4*)(dst + (size_t)i * 4) = o;
}

// ---------------- shared GEMM mainloop (128x128 tile, BK=32) ----------------
__device__ __forceinline__ void gemm_mainloop(
    const unsigned short* __restrict__ A, const unsigned short* __restrict__ B,
    int K, int m0, int n0, unsigned short* lA, unsigned short* lB, f32x4 acc[4][4]) {
  const int tid = threadIdx.x;
  const int wave = tid >> 6, lane = tid & 63;
  const int lr = lane & 15, lg = lane >> 4;
  const int wr = wave >> 1, wc = wave & 1;
  const int o0 = wave * 1024 + lane * 16;
  for (int k0 = 0; k0 < K; k0 += 32) {
    if (k0) __syncthreads();
#pragma unroll
    for (int c = 0; c < 2; ++c) {
      const int o = c * 4096 + o0;
      const int row = o >> 6;
      const int ce = (o & 63) >> 1;
      __builtin_amdgcn_global_load_lds(
          (const __attribute__((address_space(1))) void*)(A + (size_t)(m0 + row) * K + k0 + ce),
          (__attribute__((address_space(3))) void*)(lA + c * 2048 + wave * 512), 16, 0, 0);
      __builtin_amdgcn_global_load_lds(
          (const __attribute__((address_space(1))) void*)(B + (size_t)(n0 + row) * K + k0 + ce),
          (__attribute__((address_space(3))) void*)(lB + c * 2048 + wave * 512), 16, 0, 0);
    }
    __syncthreads();
    bf16x8 af[4], bfr[4];
#pragma unroll
    for (int i = 0; i < 4; ++i) {
      af[i]  = *(const bf16x8*)(lA + (wr * 64 + i * 16 + lr) * 32 + lg * 8);
      bfr[i] = *(const bf16x8*)(lB + (wc * 64 + i * 16 + lr) * 32 + lg * 8);
    }
#pragma unroll
    for (int mi = 0; mi < 4; ++mi)
#pragma unroll
      for (int ni = 0; ni < 4; ++ni)
        acc[mi][ni] = mfma16(af[mi], bfr[ni], acc[mi][ni]);
  }
}

// ---------------- GEMM1: qkv proj, scatter to head layout ----------------
// Q pre-scaled by DH^-0.5 * log2(e): flash softmax runs in log2 domain.
__global__ __launch_bounds__(256) void gemm_qkv(
    const unsigned short* __restrict__ A, const unsigned short* __restrict__ W,
    const float* __restrict__ bias,
    unsigned short* __restrict__ Qh, unsigned short* __restrict__ Kh,
    unsigned short* __restrict__ Vh) {
  __shared__ unsigned short lA[4096], lB[4096];
  f32x4 acc[4][4];
  const f32x4 z4 = {0.f, 0.f, 0.f, 0.f};
#pragma unroll
  for (int i = 0; i < 4; ++i)
#pragma unroll
    for (int j = 0; j < 4; ++j) acc[i][j] = z4;
  const int m0 = blockIdx.x * 128, n0 = blockIdx.y * 128;
  gemm_mainloop(A, W, 1024, m0, n0, lA, lB, acc);

  const int lane = threadIdx.x & 63, wave = threadIdx.x >> 6;
  const int lr = lane & 15, lg = lane >> 4;
  const int wr = wave >> 1, wc = wave & 1;
#pragma unroll
  for (int mi = 0; mi < 4; ++mi)
#pragma unroll
    for (int ni = 0; ni < 4; ++ni)
#pragma unroll
      for (int j = 0; j < 4; ++j) {
        int m = m0 + wr * 64 + mi * 16 + lg * 4 + j;
        int f = n0 + wc * 64 + ni * 16 + lr;
        float v = acc[mi][ni][j] + bias[f];
        int t = m >> 3, b = m & 7;
        int e = f & 1023, h = e >> 6, d = e & 63;
        int which = f >> 10;
        size_t idx = ((size_t)(b * 16 + h) * T_DIM + t) * DH + d;
        if (which == 0)      Qh[idx] = f2bf(v * 0.18033688011111772f);  // 0.125*log2(e)
        else if (which == 1) Kh[idx] = f2bf(v);
        else                 Vh[idx] = f2bf(v);
      }
}

// ---------------- V transpose: [n][t][d] -> [n][d][t] ----------------
__global__ __launch_bounds__(256) void transpose_v(
    const unsigned short* __restrict__ Vh, unsigned short* __restrict__ Vt) {
  __shared__ unsigned short tile[64][72];
  const int n = blockIdx.x, t0 = blockIdx.y * 64;
  const int tid = threadIdx.x;
  const int r = tid >> 3, c8 = tid & 7;
#pragma unroll
  for (int it = 0; it < 2; ++it) {
    int row = it * 32 + r;
    bf16x8 v = *(const bf16x8*)(Vh + ((size_t)n * T_DIM + t0 + row) * DH + c8 * 8);
    *(bf16x8*)&tile[row][c8 * 8] = v;
  }
  __syncthreads();
#pragma unroll
  for (int it = 0; it < 2; ++it) {
    int d = it * 32 + r;
    bf16x8 ov;
#pragma unroll
    for (int jj = 0; jj < 8; ++jj) ov[jj] = (short)tile[c8 * 8 + jj][d];
    *(bf16x8*)(Vt + ((size_t)n * DH + d) * T_DIM + t0 + c8 * 8) = ov;
  }
}

// ---------------- flash attention v4: split-s wave pairs ----------------
// Pair of waves (A=even, B=odd) shares one (head, 32-q-chunk): A does KV blocks
// [0,nb/2), B does [nb/2,nb); partial (O^T,m,l) merged via LDS with one barrier.
// grid: 2048 blocks x 4 waves = 8192 waves (fills all wave slots at 4/SIMD).
__global__ __launch_bounds__(256, 4) void flash_attn4(
    const unsigned short* __restrict__ Qh, const unsigned short* __restrict__ Kh,
    const unsigned short* __restrict__ Vt, unsigned short* __restrict__ attn) {
  __shared__ float lO[2][32][64];    // [pair][reg][lane] - conflict-free
  __shared__ float lml[2][2][64];
  const int tid = threadIdx.x;
  const int wave = tid >> 6, lane = tid & 63;
  const int lq = lane & 31, hi = lane >> 5;
  const int pl = wave >> 1;          // pair slot within block
  const int roleB = wave & 1;        // 0 = front half (A), 1 = back half (B)
  const int p = blockIdx.x * 2 + pl;
  const int j = 31 - (p >> 7);       // q-chunk index, heavy first
  const int n = p & 127;
  const int b = n >> 4, h = n & 15;
  const int q0 = j * 32;
  const int q = q0 + lq;
  const int nb = (j + 2) >> 1;       // total KV 64-blocks for this q-chunk
  const int nbA = nb >> 1;
  const int blo = roleB ? nbA : 0;
  const int bhi = roleB ? nb : nbA;

  bf16x8 qf[4];
  const unsigned short* qp = Qh + ((size_t)n * T_DIM + q) * DH + hi * 8;
#pragma unroll
  for (int kk = 0; kk < 4; ++kk) qf[kk] = *(const bf16x8*)(qp + kk * 16);

  f32x16 o0, o1;
#pragma unroll
  for (int r = 0; r < 16; ++r) { o0[r] = 0.f; o1[r] = 0.f; }
  float m_run = -1e30f, l_run = 0.f;

  const unsigned short* kbase = Kh + (size_t)n * T_DIM * DH;
  const unsigned short* vbase = Vt + (size_t)n * DH * T_DIM;

  bf16x8 kf[8];
  if (bhi > blo) {
    const unsigned short* kp = kbase + ((size_t)(blo * 64) + lq) * DH + hi * 8;
#pragma unroll
    for (int kk = 0; kk < 4; ++kk) {
      kf[kk]     = *(const bf16x8*)(kp + kk * 16);
      kf[4 + kk] = *(const bf16x8*)(kp + 32 * DH + kk * 16);
    }
  }
  const unsigned short* kp_next = kbase + ((size_t)(blo * 64 + 64) + lq) * DH + hi * 8;
  const unsigned short* vp_cur  = vbase + (size_t)lq * T_DIM + blo * 64 + hi * 8;

  for (int blk = blo; blk < bhi; ++blk) {
    const int s0 = blk << 6;
    // ---- QK^T (two independent 32-s chunks) ----
    f32x16 sA, sB;
#pragma unroll
    for (int r = 0; r < 16; ++r) { sA[r] = 0.f; sB[r] = 0.f; }
    __builtin_amdgcn_s_setprio(1);
#pragma unroll
    for (int kk = 0; kk < 4; ++kk) {
      sA = mfma32(kf[kk], qf[kk], sA);
      sB = mfma32(kf[4 + kk], qf[kk], sB);
    }
    __builtin_amdgcn_s_setprio(0);
    // ---- V fragments for this block (first: their wait is vmcnt-counted) ----
    bf16x8 vf0[4], vf1[4];
#pragma unroll
    for (int ks = 0; ks < 4; ++ks) {
      vf0[ks] = *(const bf16x8*)(vp_cur + ks * 16);
      vf1[ks] = *(const bf16x8*)(vp_cur + 32 * T_DIM + ks * 16);
    }
    vp_cur += 64;
    // ---- prefetch next K (kf dead after QK) ----
    if (blk + 1 < bhi) {
#pragma unroll
      for (int kk = 0; kk < 4; ++kk) {
        kf[kk]     = *(const bf16x8*)(kp_next + kk * 16);
        kf[4 + kk] = *(const bf16x8*)(kp_next + 32 * DH + kk * 16);
      }
      kp_next += 64 * DH;
    }
    // ---- causal mask (global last block only) ----
    if (blk == nb - 1) {
#pragma unroll
      for (int r = 0; r < 16; ++r) {
        int sp = s0 + (r & 3) + 8 * (r >> 2) + 4 * hi;
        if (sp > q)      sA[r] = -10000.0f;
        if (sp + 32 > q) sB[r] = -10000.0f;
      }
    }
    // ---- online softmax (log2 domain), 4-way reduce trees ----
    float t0 = fmaxf(sA[0], sB[0]), t1 = fmaxf(sA[1], sB[1]);
    float t2 = fmaxf(sA[2], sB[2]), t3 = fmaxf(sA[3], sB[3]);
#pragma unroll
    for (int r = 4; r < 16; r += 4) {
      t0 = fmaxf(t0, fmaxf(sA[r], sB[r]));
      t1 = fmaxf(t1, fmaxf(sA[r + 1], sB[r + 1]));
      t2 = fmaxf(t2, fmaxf(sA[r + 2], sB[r + 2]));
      t3 = fmaxf(t3, fmaxf(sA[r + 3], sB[r + 3]));
    }
    float tmax = fmaxf(fmaxf(t0, t1), fmaxf(t2, t3));
    tmax = fmaxf(tmax, __shfl_xor(tmax, 32));
    if (__any(tmax - m_run > 11.5f)) {     // defer-max
      float m_new = fmaxf(m_run, tmax);
      float sc = exp2_hw(m_run - m_new);
      l_run *= sc;
#pragma unroll
      for (int r = 0; r < 16; ++r) { o0[r] *= sc; o1[r] *= sc; }
      m_run = m_new;
    }
    float r0 = 0.f, r1 = 0.f, r2 = 0.f, r3 = 0.f;
#pragma unroll
    for (int r = 0; r < 16; r += 4) {
      sA[r] = exp2_hw(sA[r] - m_run);         r0 += sA[r];
      sA[r + 1] = exp2_hw(sA[r + 1] - m_run); r1 += sA[r + 1];
      sA[r + 2] = exp2_hw(sA[r + 2] - m_run); r2 += sA[r + 2];
      sA[r + 3] = exp2_hw(sA[r + 3] - m_run); r3 += sA[r + 3];
    }
#pragma unroll
    for (int r = 0; r < 16; r += 4) {
      sB[r] = exp2_hw(sB[r] - m_run);         r0 += sB[r];
      sB[r + 1] = exp2_hw(sB[r + 1] - m_run); r1 += sB[r + 1];
      sB[r + 2] = exp2_hw(sB[r + 2] - m_run); r2 += sB[r + 2];
      sB[r + 3] = exp2_hw(sB[r + 3] - m_run); r3 += sB[r + 3];
    }
    float rs = (r0 + r1) + (r2 + r3);
    rs += __shfl_xor(rs, 32);
    l_run += rs;
    // ---- pack P^T to bf16 fragments ----
    unsigned int pk[16];
#pragma unroll
    for (int i = 0; i < 8; ++i) pk[i]     = cvtpk_bf16(sA[2 * i], sA[2 * i + 1]);
#pragma unroll
    for (int i = 0; i < 8; ++i) pk[8 + i] = cvtpk_bf16(sB[2 * i], sB[2 * i + 1]);
    __builtin_amdgcn_s_setprio(1);
#pragma unroll
    for (int ks = 0; ks < 4; ++ks) {
      unsigned int A0 = pk[ks * 4 + 0], A1 = pk[ks * 4 + 1];
      unsigned int B0 = pk[ks * 4 + 2], B1 = pk[ks * 4 + 3];
      unsigned int xA0 = __shfl_xor(A0, 32), xA1 = __shfl_xor(A1, 32);
      unsigned int xB0 = __shfl_xor(B0, 32), xB1 = __shfl_xor(B1, 32);
      u32x4 uu;
      uu[0] = hi ? xB0 : A0;
      uu[1] = hi ? xB1 : A1;
      uu[2] = hi ? B0 : xA0;
      uu[3] = hi ? B1 : xA1;
      bf16x8 pf = __builtin_bit_cast(bf16x8, uu);
      o0 = mfma32(vf0[ks], pf, o0);
      o1 = mfma32(vf1[ks], pf, o1);
    }
    __builtin_amdgcn_s_setprio(0);
  }

  // ---- split-s merge through LDS ----
  if (roleB) {
#pragma unroll
    for (int r = 0; r < 16; ++r) {
      lO[pl][r][lane] = o0[r];
      lO[pl][16 + r][lane] = o1[r];
    }
    lml[pl][0][lane] = m_run;
    lml[pl][1][lane] = l_run;
  }
  __syncthreads();
  if (!roleB) {
    float mB = lml[pl][0][lane], lB = lml[pl][1][lane];
    float m = fmaxf(m_run, mB);
    float fA = exp2_hw(m_run - m), fB = exp2_hw(mB - m);
    float linv = 1.0f / (l_run * fA + lB * fB);
    unsigned short* op = attn + ((size_t)q * B_DIM + b) * E_DIM + h * DH;
#pragma unroll
    for (int g = 0; g < 4; ++g) {
      u16x4 w0, w1;
#pragma unroll
      for (int jj = 0; jj < 4; ++jj) {
        float a0 = (o0[g * 4 + jj] * fA + lO[pl][g * 4 + jj][lane] * fB) * linv;
        float a1 = (o1[g * 4 + jj] * fA + lO[pl][16 + g * 4 + jj][lane] * fB) * linv;
        w0[jj] = f2bf(a0);
        w1[jj] = f2bf(a1);
      }
      int d = 8 * g + 4 * hi;
      *(u16x4*)(op + d) = w0;
      *(u16x4*)(op + 32 + d) = w1;
    }
  }
}

// ---------------- GEMM2: out = attn @ out_w^T + out_b (f32 out) ----------------
__global__ __launch_bounds__(256) void gemm_out(
    const unsigned short* __restrict__ A, const unsigned short* __restrict__ W,
    const float* __restrict__ bias, float* __restrict__ out) {
  __shared__ unsigned short lA[4096], lB[4096];
  f32x4 acc[4][4];
  const f32x4 z4 = {0.f, 0.f, 0.f, 0.f};
#pragma unroll
  for (int i = 0; i < 4; ++i)
#pragma unroll
    for (int j = 0; j < 4; ++j) acc[i][j] = z4;
  const int m0 = blockIdx.x * 128, n0 = blockIdx.y * 128;
  gemm_mainloop(A, W, 1024, m0, n0, lA, lB, acc);

  const int lane = threadIdx.x & 63, wave = threadIdx.x >> 6;
  const int lr = lane & 15, lg = lane >> 4;
  const int wr = wave >> 1, wc = wave & 1;
#pragma unroll
  for (int mi = 0; mi < 4; ++mi)
#pragma unroll
    for (int ni = 0; ni < 4; ++ni)
#pragma unroll
      for (int j = 0; j < 4; ++j) {
        int m = m0 + wr * 64 + mi * 16 + lg * 4 + j;
        int f = n0 + wc * 64 + ni * 16 + lr;
        out[(size_t)m * E_DIM + f] = acc[mi][ni][j] + bias[f];
      }
}

extern "C" void kernel_launch(void* const* d_in, const int* in_sizes, int n_in,
                              void* d_out, int out_size, void* d_ws, size_t ws_size,
                              hipStream_t stream) {
  const float* query = (const float*)d_in[0];
  const float* qkv_w = (const float*)d_in[1];
  const float* qkv_b = (const float*)d_in[2];
  const float* out_w = (const float*)d_in[3];
  const float* out_b = (const float*)d_in[4];
  float* out = (float*)d_out;

  char* ws = (char*)d_ws;
  unsigned short* Abf  = (unsigned short*)(ws);
  unsigned short* Wbf  = (unsigned short*)(ws + (size_t)(16u << 20));
  unsigned short* OWbf = (unsigned short*)(ws + (size_t)(22u << 20));
  unsigned short* Qh   = (unsigned short*)(ws + (size_t)(24u << 20));
  unsigned short* Kh   = (unsigned short*)(ws + (size_t)(40u << 20));
  unsigned short* Vh   = (unsigned short*)(ws + (size_t)(56u << 20));
  unsigned short* Vt   = (unsigned short*)(ws + (size_t)(72u << 20));
  unsigned short* attn = Abf;  // alias: query-bf16 dead after gemm_qkv

  cast_f32_to_bf16<<<8192, 256, 0, stream>>>(query, Abf, 8388608 / 4);
  cast_f32_to_bf16<<<3072, 256, 0, stream>>>(qkv_w, Wbf, 3145728 / 4);
  cast_f32_to_bf16<<<1024, 256, 0, stream>>>(out_w, OWbf, 1048576 / 4);
  gemm_qkv<<<dim3(64, 24), 256, 0, stream>>>(Abf, Wbf, qkv_b, Qh, Kh, Vh);
  transpose_v<<<dim3(128, 16), 256, 0, stream>>>(Vh, Vt);
  flash_attn4<<<2048, 256, 0, stream>>>(Qh, Kh, Vt, attn);
  gemm_out<<<dim3(64, 8), 256, 0, stream>>>(attn, OWbf, out_b, out);
}

// Round 5
// 188.059 us; speedup vs baseline: 1.4382x; 1.4382x over previous
//
#include <hip/hip_runtime.h>

typedef __attribute__((ext_vector_type(4))) float f32x4;
typedef __attribute__((ext_vector_type(16))) float f32x16;
typedef __attribute__((ext_vector_type(8))) short bf16x8;
typedef __attribute__((ext_vector_type(4))) unsigned short u16x4;
typedef __attribute__((ext_vector_type(4))) unsigned int u32x4;

#define T_DIM 1024
#define B_DIM 8
#define E_DIM 1024
#define H_DIM 16
#define DH 64

__device__ __forceinline__ unsigned short f2bf(float f) {
  unsigned int u = __builtin_bit_cast(unsigned int, f);
  u += 0x7fffu + ((u >> 16) & 1u);   // RNE
  return (unsigned short)(u >> 16);
}

__device__ __forceinline__ unsigned int cvtpk_bf16(float lo, float hi) {
  unsigned int r;
  asm("v_cvt_pk_bf16_f32 %0, %1, %2" : "=v"(r) : "v"(lo), "v"(hi));
  return r;
}

__device__ __forceinline__ float exp2_hw(float x) {   // bare v_exp_f32 (2^x)
  float r;
  asm("v_exp_f32 %0, %1" : "=v"(r) : "v"(x));
  return r;
}

__device__ __forceinline__ f32x4 mfma16(bf16x8 a, bf16x8 b, f32x4 c) {
  return __builtin_amdgcn_mfma_f32_16x16x32_bf16(a, b, c, 0, 0, 0);
}
__device__ __forceinline__ f32x16 mfma32(bf16x8 a, bf16x8 b, f32x16 c) {
  return __builtin_amdgcn_mfma_f32_32x32x16_bf16(a, b, c, 0, 0, 0);
}

// ---------------- cast f32 -> bf16, 4 elems/thread ----------------
__global__ __launch_bounds__(256) void cast_f32_to_bf16(
    const float* __restrict__ src, unsigned short* __restrict__ dst, int n4) {
  int i = blockIdx.x * 256 + threadIdx.x;
  if (i >= n4) return;
  f32x4 v = *(const f32x4*)(src + (size_t)i * 4);
  u16x4 o;
  o[0] = f2bf(v[0]); o[1] = f2bf(v[1]); o[2] = f2bf(v[2]); o[3] = f2bf(v[3]);
  *(u16x4*)(dst + (size_t)i * 4) = o;
}

// ---------------- shared GEMM mainloop (128x128 tile, BK=32) ----------------
__device__ __forceinline__ void gemm_mainloop(
    const unsigned short* __restrict__ A, const unsigned short* __restrict__ B,
    int K, int m0, int n0, unsigned short* lA, unsigned short* lB, f32x4 acc[4][4]) {
  const int tid = threadIdx.x;
  const int wave = tid >> 6, lane = tid & 63;
  const int lr = lane & 15, lg = lane >> 4;
  const int wr = wave >> 1, wc = wave & 1;
  const int o0 = wave * 1024 + lane * 16;
  for (int k0 = 0; k0 < K; k0 += 32) {
    if (k0) __syncthreads();
#pragma unroll
    for (int c = 0; c < 2; ++c) {
      const int o = c * 4096 + o0;
      const int row = o >> 6;
      const int ce = (o & 63) >> 1;
      __builtin_amdgcn_global_load_lds(
          (const __attribute__((address_space(1))) void*)(A + (size_t)(m0 + row) * K + k0 + ce),
          (__attribute__((address_space(3))) void*)(lA + c * 2048 + wave * 512), 16, 0, 0);
      __builtin_amdgcn_global_load_lds(
          (const __attribute__((address_space(1))) void*)(B + (size_t)(n0 + row) * K + k0 + ce),
          (__attribute__((address_space(3))) void*)(lB + c * 2048 + wave * 512), 16, 0, 0);
    }
    __syncthreads();
    bf16x8 af[4], bfr[4];
#pragma unroll
    for (int i = 0; i < 4; ++i) {
      af[i]  = *(const bf16x8*)(lA + (wr * 64 + i * 16 + lr) * 32 + lg * 8);
      bfr[i] = *(const bf16x8*)(lB + (wc * 64 + i * 16 + lr) * 32 + lg * 8);
    }
#pragma unroll
    for (int mi = 0; mi < 4; ++mi)
#pragma unroll
      for (int ni = 0; ni < 4; ++ni)
        acc[mi][ni] = mfma16(af[mi], bfr[ni], acc[mi][ni]);
  }
}

// ---------------- GEMM1: qkv proj, scatter to head layout ----------------
// Q pre-scaled by DH^-0.5 * log2(e): flash softmax runs in log2 domain.
__global__ __launch_bounds__(256) void gemm_qkv(
    const unsigned short* __restrict__ A, const unsigned short* __restrict__ W,
    const float* __restrict__ bias,
    unsigned short* __restrict__ Qh, unsigned short* __restrict__ Kh,
    unsigned short* __restrict__ Vh) {
  __shared__ unsigned short lA[4096], lB[4096];
  f32x4 acc[4][4];
  const f32x4 z4 = {0.f, 0.f, 0.f, 0.f};
#pragma unroll
  for (int i = 0; i < 4; ++i)
#pragma unroll
    for (int j = 0; j < 4; ++j) acc[i][j] = z4;
  const int m0 = blockIdx.x * 128, n0 = blockIdx.y * 128;
  gemm_mainloop(A, W, 1024, m0, n0, lA, lB, acc);

  const int lane = threadIdx.x & 63, wave = threadIdx.x >> 6;
  const int lr = lane & 15, lg = lane >> 4;
  const int wr = wave >> 1, wc = wave & 1;
#pragma unroll
  for (int mi = 0; mi < 4; ++mi)
#pragma unroll
    for (int ni = 0; ni < 4; ++ni)
#pragma unroll
      for (int j = 0; j < 4; ++j) {
        int m = m0 + wr * 64 + mi * 16 + lg * 4 + j;
        int f = n0 + wc * 64 + ni * 16 + lr;
        float v = acc[mi][ni][j] + bias[f];
        int t = m >> 3, b = m & 7;
        int e = f & 1023, h = e >> 6, d = e & 63;
        int which = f >> 10;
        size_t idx = ((size_t)(b * 16 + h) * T_DIM + t) * DH + d;
        if (which == 0)      Qh[idx] = f2bf(v * 0.18033688011111772f);  // 0.125*log2(e)
        else if (which == 1) Kh[idx] = f2bf(v);
        else                 Vh[idx] = f2bf(v);
      }
}

// ---------------- V transpose: [n][t][d] -> [n][d][t] ----------------
__global__ __launch_bounds__(256) void transpose_v(
    const unsigned short* __restrict__ Vh, unsigned short* __restrict__ Vt) {
  __shared__ unsigned short tile[64][72];
  const int n = blockIdx.x, t0 = blockIdx.y * 64;
  const int tid = threadIdx.x;
  const int r = tid >> 3, c8 = tid & 7;
#pragma unroll
  for (int it = 0; it < 2; ++it) {
    int row = it * 32 + r;
    bf16x8 v = *(const bf16x8*)(Vh + ((size_t)n * T_DIM + t0 + row) * DH + c8 * 8);
    *(bf16x8*)&tile[row][c8 * 8] = v;
  }
  __syncthreads();
#pragma unroll
  for (int it = 0; it < 2; ++it) {
    int d = it * 32 + r;
    bf16x8 ov;
#pragma unroll
    for (int jj = 0; jj < 8; ++jj) ov[jj] = (short)tile[c8 * 8 + jj][d];
    *(bf16x8*)(Vt + ((size_t)n * DH + d) * T_DIM + t0 + c8 * 8) = ov;
  }
}

// ---------------- flash attention v5: split-s wave pairs (no VGPR cap) ----------------
// Pair of waves (A=even, B=odd) shares one (head, 32-q-chunk): A does KV blocks
// [0,nb/2), B does [nb/2,nb); partial (O^T,m,l) merged via LDS with one barrier.
// grid: 2048 blocks x 4 waves = 8192 near-uniform waves.
// NOTE: no min-waves launch bound — R4's (256,4) forced VGPR=64 and spilled
// ~600MB/dispatch to scratch. Let the allocator take ~120 VGPR (4 waves/SIMD).
__global__ __launch_bounds__(256) void flash_attn5(
    const unsigned short* __restrict__ Qh, const unsigned short* __restrict__ Kh,
    const unsigned short* __restrict__ Vt, unsigned short* __restrict__ attn) {
  __shared__ float lO[2][32][64];    // [pair][reg][lane] - conflict-free
  __shared__ float lml[2][2][64];
  const int tid = threadIdx.x;
  const int wave = tid >> 6, lane = tid & 63;
  const int lq = lane & 31, hi = lane >> 5;
  const int pl = wave >> 1;          // pair slot within block
  const int roleB = wave & 1;        // 0 = front half (A), 1 = back half (B)
  const int p = blockIdx.x * 2 + pl;
  const int j = 31 - (p >> 7);       // q-chunk index, heavy first
  const int n = p & 127;
  const int b = n >> 4, h = n & 15;
  const int q0 = j * 32;
  const int q = q0 + lq;
  const int nb = (j + 2) >> 1;       // total KV 64-blocks for this q-chunk
  const int nbA = nb >> 1;
  const int blo = roleB ? nbA : 0;
  const int bhi = roleB ? nb : nbA;

  bf16x8 qf[4];
  const unsigned short* qp = Qh + ((size_t)n * T_DIM + q) * DH + hi * 8;
#pragma unroll
  for (int kk = 0; kk < 4; ++kk) qf[kk] = *(const bf16x8*)(qp + kk * 16);

  f32x16 o0, o1;
#pragma unroll
  for (int r = 0; r < 16; ++r) { o0[r] = 0.f; o1[r] = 0.f; }
  float m_run = -1e30f, l_run = 0.f;

  const unsigned short* kbase = Kh + (size_t)n * T_DIM * DH;
  const unsigned short* vbase = Vt + (size_t)n * DH * T_DIM;

  bf16x8 kf[8];
  if (bhi > blo) {
    const unsigned short* kp = kbase + ((size_t)(blo * 64) + lq) * DH + hi * 8;
#pragma unroll
    for (int kk = 0; kk < 4; ++kk) {
      kf[kk]     = *(const bf16x8*)(kp + kk * 16);
      kf[4 + kk] = *(const bf16x8*)(kp + 32 * DH + kk * 16);
    }
  }
  const unsigned short* kp_next = kbase + ((size_t)(blo * 64 + 64) + lq) * DH + hi * 8;
  const unsigned short* vp_cur  = vbase + (size_t)lq * T_DIM + blo * 64 + hi * 8;

  for (int blk = blo; blk < bhi; ++blk) {
    const int s0 = blk << 6;
    // ---- QK^T (two independent 32-s chunks) ----
    f32x16 sA, sB;
#pragma unroll
    for (int r = 0; r < 16; ++r) { sA[r] = 0.f; sB[r] = 0.f; }
    __builtin_amdgcn_s_setprio(1);
#pragma unroll
    for (int kk = 0; kk < 4; ++kk) {
      sA = mfma32(kf[kk], qf[kk], sA);
      sB = mfma32(kf[4 + kk], qf[kk], sB);
    }
    __builtin_amdgcn_s_setprio(0);
    // ---- V fragments for this block ----
    bf16x8 vf0[4], vf1[4];
#pragma unroll
    for (int ks = 0; ks < 4; ++ks) {
      vf0[ks] = *(const bf16x8*)(vp_cur + ks * 16);
      vf1[ks] = *(const bf16x8*)(vp_cur + 32 * T_DIM + ks * 16);
    }
    vp_cur += 64;
    // ---- prefetch next K (kf dead after QK) ----
    if (blk + 1 < bhi) {
#pragma unroll
      for (int kk = 0; kk < 4; ++kk) {
        kf[kk]     = *(const bf16x8*)(kp_next + kk * 16);
        kf[4 + kk] = *(const bf16x8*)(kp_next + 32 * DH + kk * 16);
      }
      kp_next += 64 * DH;
    }
    // ---- causal mask (global last block only) ----
    if (blk == nb - 1) {
#pragma unroll
      for (int r = 0; r < 16; ++r) {
        int sp = s0 + (r & 3) + 8 * (r >> 2) + 4 * hi;
        if (sp > q)      sA[r] = -10000.0f;
        if (sp + 32 > q) sB[r] = -10000.0f;
      }
    }
    // ---- online softmax (log2 domain), 4-way reduce trees ----
    float t0 = fmaxf(sA[0], sB[0]), t1 = fmaxf(sA[1], sB[1]);
    float t2 = fmaxf(sA[2], sB[2]), t3 = fmaxf(sA[3], sB[3]);
#pragma unroll
    for (int r = 4; r < 16; r += 4) {
      t0 = fmaxf(t0, fmaxf(sA[r], sB[r]));
      t1 = fmaxf(t1, fmaxf(sA[r + 1], sB[r + 1]));
      t2 = fmaxf(t2, fmaxf(sA[r + 2], sB[r + 2]));
      t3 = fmaxf(t3, fmaxf(sA[r + 3], sB[r + 3]));
    }
    float tmax = fmaxf(fmaxf(t0, t1), fmaxf(t2, t3));
    tmax = fmaxf(tmax, __shfl_xor(tmax, 32));
    if (__any(tmax - m_run > 11.5f)) {     // defer-max
      float m_new = fmaxf(m_run, tmax);
      float sc = exp2_hw(m_run - m_new);
      l_run *= sc;
#pragma unroll
      for (int r = 0; r < 16; ++r) { o0[r] *= sc; o1[r] *= sc; }
      m_run = m_new;
    }
    float r0 = 0.f, r1 = 0.f, r2 = 0.f, r3 = 0.f;
#pragma unroll
    for (int r = 0; r < 16; r += 4) {
      sA[r] = exp2_hw(sA[r] - m_run);         r0 += sA[r];
      sA[r + 1] = exp2_hw(sA[r + 1] - m_run); r1 += sA[r + 1];
      sA[r + 2] = exp2_hw(sA[r + 2] - m_run); r2 += sA[r + 2];
      sA[r + 3] = exp2_hw(sA[r + 3] - m_run); r3 += sA[r + 3];
    }
#pragma unroll
    for (int r = 0; r < 16; r += 4) {
      sB[r] = exp2_hw(sB[r] - m_run);         r0 += sB[r];
      sB[r + 1] = exp2_hw(sB[r + 1] - m_run); r1 += sB[r + 1];
      sB[r + 2] = exp2_hw(sB[r + 2] - m_run); r2 += sB[r + 2];
      sB[r + 3] = exp2_hw(sB[r + 3] - m_run); r3 += sB[r + 3];
    }
    float rs = (r0 + r1) + (r2 + r3);
    rs += __shfl_xor(rs, 32);
    l_run += rs;
    // ---- pack P^T to bf16 fragments ----
    unsigned int pk[16];
#pragma unroll
    for (int i = 0; i < 8; ++i) pk[i]     = cvtpk_bf16(sA[2 * i], sA[2 * i + 1]);
#pragma unroll
    for (int i = 0; i < 8; ++i) pk[8 + i] = cvtpk_bf16(sB[2 * i], sB[2 * i + 1]);
    __builtin_amdgcn_s_setprio(1);
#pragma unroll
    for (int ks = 0; ks < 4; ++ks) {
      unsigned int A0 = pk[ks * 4 + 0], A1 = pk[ks * 4 + 1];
      unsigned int B0 = pk[ks * 4 + 2], B1 = pk[ks * 4 + 3];
      unsigned int xA0 = __shfl_xor(A0, 32), xA1 = __shfl_xor(A1, 32);
      unsigned int xB0 = __shfl_xor(B0, 32), xB1 = __shfl_xor(B1, 32);
      u32x4 uu;
      uu[0] = hi ? xB0 : A0;
      uu[1] = hi ? xB1 : A1;
      uu[2] = hi ? B0 : xA0;
      uu[3] = hi ? B1 : xA1;
      bf16x8 pf = __builtin_bit_cast(bf16x8, uu);
      o0 = mfma32(vf0[ks], pf, o0);
      o1 = mfma32(vf1[ks], pf, o1);
    }
    __builtin_amdgcn_s_setprio(0);
  }

  // ---- split-s merge through LDS ----
  if (roleB) {
#pragma unroll
    for (int r = 0; r < 16; ++r) {
      lO[pl][r][lane] = o0[r];
      lO[pl][16 + r][lane] = o1[r];
    }
    lml[pl][0][lane] = m_run;
    lml[pl][1][lane] = l_run;
  }
  __syncthreads();
  if (!roleB) {
    float mB = lml[pl][0][lane], lB = lml[pl][1][lane];
    float m = fmaxf(m_run, mB);
    float fA = exp2_hw(m_run - m), fB = exp2_hw(mB - m);
    float linv = 1.0f / (l_run * fA + lB * fB);
    unsigned short* op = attn + ((size_t)q * B_DIM + b) * E_DIM + h * DH;
#pragma unroll
    for (int g = 0; g < 4; ++g) {
      u16x4 w0, w1;
#pragma unroll
      for (int jj = 0; jj < 4; ++jj) {
        float a0 = (o0[g * 4 + jj] * fA + lO[pl][g * 4 + jj][lane] * fB) * linv;
        float a1 = (o1[g * 4 + jj] * fA + lO[pl][16 + g * 4 + jj][lane] * fB) * linv;
        w0[jj] = f2bf(a0);
        w1[jj] = f2bf(a1);
      }
      int d = 8 * g + 4 * hi;
      *(u16x4*)(op + d) = w0;
      *(u16x4*)(op + 32 + d) = w1;
    }
  }
}

// ---------------- GEMM2: out = attn @ out_w^T + out_b (f32 out) ----------------
__global__ __launch_bounds__(256) void gemm_out(
    const unsigned short* __restrict__ A, const unsigned short* __restrict__ W,
    const float* __restrict__ bias, float* __restrict__ out) {
  __shared__ unsigned short lA[4096], lB[4096];
  f32x4 acc[4][4];
  const f32x4 z4 = {0.f, 0.f, 0.f, 0.f};
#pragma unroll
  for (int i = 0; i < 4; ++i)
#pragma unroll
    for (int j = 0; j < 4; ++j) acc[i][j] = z4;
  const int m0 = blockIdx.x * 128, n0 = blockIdx.y * 128;
  gemm_mainloop(A, W, 1024, m0, n0, lA, lB, acc);

  const int lane = threadIdx.x & 63, wave = threadIdx.x >> 6;
  const int lr = lane & 15, lg = lane >> 4;
  const int wr = wave >> 1, wc = wave & 1;
#pragma unroll
  for (int mi = 0; mi < 4; ++mi)
#pragma unroll
    for (int ni = 0; ni < 4; ++ni)
#pragma unroll
      for (int j = 0; j < 4; ++j) {
        int m = m0 + wr * 64 + mi * 16 + lg * 4 + j;
        int f = n0 + wc * 64 + ni * 16 + lr;
        out[(size_t)m * E_DIM + f] = acc[mi][ni][j] + bias[f];
      }
}

extern "C" void kernel_launch(void* const* d_in, const int* in_sizes, int n_in,
                              void* d_out, int out_size, void* d_ws, size_t ws_size,
                              hipStream_t stream) {
  const float* query = (const float*)d_in[0];
  const float* qkv_w = (const float*)d_in[1];
  const float* qkv_b = (const float*)d_in[2];
  const float* out_w = (const float*)d_in[3];
  const float* out_b = (const float*)d_in[4];
  float* out = (float*)d_out;

  char* ws = (char*)d_ws;
  unsigned short* Abf  = (unsigned short*)(ws);
  unsigned short* Wbf  = (unsigned short*)(ws + (size_t)(16u << 20));
  unsigned short* OWbf = (unsigned short*)(ws + (size_t)(22u << 20));
  unsigned short* Qh   = (unsigned short*)(ws + (size_t)(24u << 20));
  unsigned short* Kh   = (unsigned short*)(ws + (size_t)(40u << 20));
  unsigned short* Vh   = (unsigned short*)(ws + (size_t)(56u << 20));
  unsigned short* Vt   = (unsigned short*)(ws + (size_t)(72u << 20));
  unsigned short* attn = Abf;  // alias: query-bf16 dead after gemm_qkv

  cast_f32_to_bf16<<<8192, 256, 0, stream>>>(query, Abf, 8388608 / 4);
  cast_f32_to_bf16<<<3072, 256, 0, stream>>>(qkv_w, Wbf, 3145728 / 4);
  cast_f32_to_bf16<<<1024, 256, 0, stream>>>(out_w, OWbf, 1048576 / 4);
  gemm_qkv<<<dim3(64, 24), 256, 0, stream>>>(Abf, Wbf, qkv_b, Qh, Kh, Vh);
  transpose_v<<<dim3(128, 16), 256, 0, stream>>>(Vh, Vt);
  flash_attn5<<<2048, 256, 0, stream>>>(Qh, Kh, Vt, attn);
  gemm_out<<<dim3(64, 8), 256, 0, stream>>>(attn, OWbf, out_b, out);
}

// Round 6
// 163.530 us; speedup vs baseline: 1.6539x; 1.1500x over previous
//
#include <hip/hip_runtime.h>

typedef __attribute__((ext_vector_type(4))) float f32x4;
typedef __attribute__((ext_vector_type(16))) float f32x16;
typedef __attribute__((ext_vector_type(8))) short bf16x8;
typedef __attribute__((ext_vector_type(4))) unsigned short u16x4;
typedef __attribute__((ext_vector_type(4))) unsigned int u32x4;

#define T_DIM 1024
#define B_DIM 8
#define E_DIM 1024
#define H_DIM 16
#define DH 64

__device__ __forceinline__ unsigned short f2bf(float f) {
  unsigned int u = __builtin_bit_cast(unsigned int, f);
  u += 0x7fffu + ((u >> 16) & 1u);   // RNE
  return (unsigned short)(u >> 16);
}

__device__ __forceinline__ unsigned int cvtpk_bf16(float lo, float hi) {
  unsigned int r;
  asm("v_cvt_pk_bf16_f32 %0, %1, %2" : "=v"(r) : "v"(lo), "v"(hi));
  return r;
}

__device__ __forceinline__ float exp2_hw(float x) {   // bare v_exp_f32 (2^x)
  float r;
  asm("v_exp_f32 %0, %1" : "=v"(r) : "v"(x));
  return r;
}

__device__ __forceinline__ f32x4 mfma16(bf16x8 a, bf16x8 b, f32x4 c) {
  return __builtin_amdgcn_mfma_f32_16x16x32_bf16(a, b, c, 0, 0, 0);
}
__device__ __forceinline__ f32x16 mfma32(bf16x8 a, bf16x8 b, f32x16 c) {
  return __builtin_amdgcn_mfma_f32_32x32x16_bf16(a, b, c, 0, 0, 0);
}

// ---------------- cast f32 -> bf16, 4 elems/thread ----------------
__global__ __launch_bounds__(256) void cast_f32_to_bf16(
    const float* __restrict__ src, unsigned short* __restrict__ dst, int n4) {
  int i = blockIdx.x * 256 + threadIdx.x;
  if (i >= n4) return;
  f32x4 v = *(const f32x4*)(src + (size_t)i * 4);
  u16x4 o;
  o[0] = f2bf(v[0]); o[1] = f2bf(v[1]); o[2] = f2bf(v[2]); o[3] = f2bf(v[3]);
  *(u16x4*)(dst + (size_t)i * 4) = o;
}

// ---------------- shared GEMM mainloop (128x128 tile, BK=32) ----------------
__device__ __forceinline__ void gemm_mainloop(
    const unsigned short* __restrict__ A, const unsigned short* __restrict__ B,
    int K, int m0, int n0, unsigned short* lA, unsigned short* lB, f32x4 acc[4][4]) {
  const int tid = threadIdx.x;
  const int wave = tid >> 6, lane = tid & 63;
  const int lr = lane & 15, lg = lane >> 4;
  const int wr = wave >> 1, wc = wave & 1;
  const int o0 = wave * 1024 + lane * 16;
  for (int k0 = 0; k0 < K; k0 += 32) {
    if (k0) __syncthreads();
#pragma unroll
    for (int c = 0; c < 2; ++c) {
      const int o = c * 4096 + o0;
      const int row = o >> 6;
      const int ce = (o & 63) >> 1;
      __builtin_amdgcn_global_load_lds(
          (const __attribute__((address_space(1))) void*)(A + (size_t)(m0 + row) * K + k0 + ce),
          (__attribute__((address_space(3))) void*)(lA + c * 2048 + wave * 512), 16, 0, 0);
      __builtin_amdgcn_global_load_lds(
          (const __attribute__((address_space(1))) void*)(B + (size_t)(n0 + row) * K + k0 + ce),
          (__attribute__((address_space(3))) void*)(lB + c * 2048 + wave * 512), 16, 0, 0);
    }
    __syncthreads();
    bf16x8 af[4], bfr[4];
#pragma unroll
    for (int i = 0; i < 4; ++i) {
      af[i]  = *(const bf16x8*)(lA + (wr * 64 + i * 16 + lr) * 32 + lg * 8);
      bfr[i] = *(const bf16x8*)(lB + (wc * 64 + i * 16 + lr) * 32 + lg * 8);
    }
#pragma unroll
    for (int mi = 0; mi < 4; ++mi)
#pragma unroll
      for (int ni = 0; ni < 4; ++ni)
        acc[mi][ni] = mfma16(af[mi], bfr[ni], acc[mi][ni]);
  }
}

// ---------------- GEMM1: qkv proj, scatter to head layout ----------------
// Q pre-scaled by DH^-0.5 * log2(e): flash softmax runs in log2 domain.
__global__ __launch_bounds__(256) void gemm_qkv(
    const unsigned short* __restrict__ A, const unsigned short* __restrict__ W,
    const float* __restrict__ bias,
    unsigned short* __restrict__ Qh, unsigned short* __restrict__ Kh,
    unsigned short* __restrict__ Vh) {
  __shared__ unsigned short lA[4096], lB[4096];
  f32x4 acc[4][4];
  const f32x4 z4 = {0.f, 0.f, 0.f, 0.f};
#pragma unroll
  for (int i = 0; i < 4; ++i)
#pragma unroll
    for (int j = 0; j < 4; ++j) acc[i][j] = z4;
  const int m0 = blockIdx.x * 128, n0 = blockIdx.y * 128;
  gemm_mainloop(A, W, 1024, m0, n0, lA, lB, acc);

  const int lane = threadIdx.x & 63, wave = threadIdx.x >> 6;
  const int lr = lane & 15, lg = lane >> 4;
  const int wr = wave >> 1, wc = wave & 1;
#pragma unroll
  for (int mi = 0; mi < 4; ++mi)
#pragma unroll
    for (int ni = 0; ni < 4; ++ni)
#pragma unroll
      for (int j = 0; j < 4; ++j) {
        int m = m0 + wr * 64 + mi * 16 + lg * 4 + j;
        int f = n0 + wc * 64 + ni * 16 + lr;
        float v = acc[mi][ni][j] + bias[f];
        int t = m >> 3, b = m & 7;
        int e = f & 1023, h = e >> 6, d = e & 63;
        int which = f >> 10;
        size_t idx = ((size_t)(b * 16 + h) * T_DIM + t) * DH + d;
        if (which == 0)      Qh[idx] = f2bf(v * 0.18033688011111772f);  // 0.125*log2(e)
        else if (which == 1) Kh[idx] = f2bf(v);
        else                 Vh[idx] = f2bf(v);
      }
}

// ---------------- V transpose: [n][t][d] -> [n][d][t] ----------------
__global__ __launch_bounds__(256) void transpose_v(
    const unsigned short* __restrict__ Vh, unsigned short* __restrict__ Vt) {
  __shared__ unsigned short tile[64][72];
  const int n = blockIdx.x, t0 = blockIdx.y * 64;
  const int tid = threadIdx.x;
  const int r = tid >> 3, c8 = tid & 7;
#pragma unroll
  for (int it = 0; it < 2; ++it) {
    int row = it * 32 + r;
    bf16x8 v = *(const bf16x8*)(Vh + ((size_t)n * T_DIM + t0 + row) * DH + c8 * 8);
    *(bf16x8*)&tile[row][c8 * 8] = v;
  }
  __syncthreads();
#pragma unroll
  for (int it = 0; it < 2; ++it) {
    int d = it * 32 + r;
    bf16x8 ov;
#pragma unroll
    for (int jj = 0; jj < 8; ++jj) ov[jj] = (short)tile[c8 * 8 + jj][d];
    *(bf16x8*)(Vt + ((size_t)n * DH + d) * T_DIM + t0 + c8 * 8) = ov;
  }
}

// ---------------- flash attention v6: block-cooperative coalesced K/V staging ----------------
// Block = (head n, 128-q tile) x 4 waves (32 q each). Per 64-s KV tile, K [64s][64d]
// and V^T [64d][64s] are staged into XOR-swizzled LDS (double-buffered) via
// global_load_lds (coalesced 1KB/instr, shared by all 4 waves). Counted vmcnt(4)
// keeps next-tile stages in flight across raw s_barriers. Compute = swapped-QK^T
// 32x32 + in-register log2 softmax + cvt_pk/shfl P-pack (same as v5).
// Swizzle: LDS[row][colbyte ^ ((row&7)<<4)] = global[row][colbyte]  (rule #21:
// linear dest + inverse-swizzled per-lane SOURCE + swizzled read).
__global__ __launch_bounds__(256) void flash_attn6(
    const unsigned short* __restrict__ Qh, const unsigned short* __restrict__ Kh,
    const unsigned short* __restrict__ Vt, unsigned short* __restrict__ attn) {
  __shared__ unsigned short lds[2][2][4096];   // [buf][K=0/V=1][64 rows x 64 elems]
  const int tid = threadIdx.x;
  const int wave = tid >> 6, lane = tid & 63;
  const int lq = lane & 31, hi = lane >> 5;
  const int bid = blockIdx.x;
  const int qt = 7 - (bid >> 7);       // heavy q-tiles first
  const int n = bid & 127;
  const int b = n >> 4, h = n & 15;
  const int q0w = qt * 128 + wave * 32;
  const int q = q0w + lq;
  const int nbb = 2 * qt + 2;          // KV 64-tiles this block processes
  const int mynb = (q0w + 95) >> 6;    // this wave computes tiles < mynb

  const unsigned short* kh_n = Kh + (size_t)n * (T_DIM * DH);
  const unsigned short* vt_n = Vt + (size_t)n * (DH * T_DIM);

  // staging source swizzle (per lane): dest slot row r = instr*8 + (lane>>3),
  // dest colbyte = (lane&7)*16; source colelem = 8*((lane&7) ^ (lane>>3))
  const int rlo = lane >> 3;
  const int csw = 8 * ((lane & 7) ^ rlo);

#define STAGE(S0, BUF)                                                          \
  {                                                                             \
    _Pragma("unroll")                                                           \
    for (int m_ = 0; m_ < 2; ++m_) {                                            \
      const int instr_ = wave * 2 + m_;                                         \
      const int r_ = instr_ * 8 + rlo;                                          \
      __builtin_amdgcn_global_load_lds(                                         \
          (const __attribute__((address_space(1))) void*)(kh_n + (size_t)((S0) + r_) * DH + csw), \
          (__attribute__((address_space(3))) void*)(&lds[BUF][0][instr_ * 512]), 16, 0, 0); \
      __builtin_amdgcn_global_load_lds(                                         \
          (const __attribute__((address_space(1))) void*)(vt_n + (size_t)r_ * T_DIM + (S0) + csw), \
          (__attribute__((address_space(3))) void*)(&lds[BUF][1][instr_ * 512]), 16, 0, 0); \
    }                                                                           \
  }

  // Q^T B-fragments
  bf16x8 qf[4];
  const unsigned short* qp = Qh + ((size_t)n * T_DIM + q) * DH + hi * 8;
#pragma unroll
  for (int kk = 0; kk < 4; ++kk) qf[kk] = *(const bf16x8*)(qp + kk * 16);

  f32x16 o0, o1;
#pragma unroll
  for (int r = 0; r < 16; ++r) { o0[r] = 0.f; o1[r] = 0.f; }
  float m_run = -1e30f, l_run = 0.f;

  // prologue: stage tile 0
  STAGE(0, 0);
  asm volatile("s_waitcnt vmcnt(0)");
  __builtin_amdgcn_s_barrier();

  const int swz = (lq & 7) << 4;       // read-side XOR (byte units)

  for (int i = 0; i < nbb; ++i) {
    const int cur = i & 1;
    if (i + 1 < nbb) {
      STAGE((i + 1) * 64, cur ^ 1);
      asm volatile("s_waitcnt vmcnt(4)");   // own 4 prefetch loads stay in flight
    } else {
      asm volatile("s_waitcnt vmcnt(0)");
    }
    __builtin_amdgcn_s_barrier();
    __builtin_amdgcn_sched_barrier(0);

    if (i < mynb) {
      const int s0 = i * 64;
      const unsigned short* kb = lds[cur][0];
      const unsigned short* vb = lds[cur][1];
      // ---- QK^T: A = K rows (s'), B = Q^T ----
      f32x16 sA, sB;
#pragma unroll
      for (int r = 0; r < 16; ++r) { sA[r] = 0.f; sB[r] = 0.f; }
      __builtin_amdgcn_s_setprio(1);
#pragma unroll
      for (int kk = 0; kk < 4; ++kk) {
        const int cb = ((kk * 32 + hi * 16) ^ swz) >> 1;   // element offset
        bf16x8 ka = *(const bf16x8*)(kb + lq * 64 + cb);
        bf16x8 kbf = *(const bf16x8*)(kb + (32 + lq) * 64 + cb);
        sA = mfma32(ka, qf[kk], sA);
        sB = mfma32(kbf, qf[kk], sB);
      }
      __builtin_amdgcn_s_setprio(0);
      // ---- causal mask (wave's last tile only) ----
      if (i == mynb - 1) {
#pragma unroll
        for (int r = 0; r < 16; ++r) {
          int sp = s0 + (r & 3) + 8 * (r >> 2) + 4 * hi;
          if (sp > q)      sA[r] = -10000.0f;
          if (sp + 32 > q) sB[r] = -10000.0f;
        }
      }
      // ---- online softmax (log2 domain), 4-way trees ----
      float t0 = fmaxf(sA[0], sB[0]), t1 = fmaxf(sA[1], sB[1]);
      float t2 = fmaxf(sA[2], sB[2]), t3 = fmaxf(sA[3], sB[3]);
#pragma unroll
      for (int r = 4; r < 16; r += 4) {
        t0 = fmaxf(t0, fmaxf(sA[r], sB[r]));
        t1 = fmaxf(t1, fmaxf(sA[r + 1], sB[r + 1]));
        t2 = fmaxf(t2, fmaxf(sA[r + 2], sB[r + 2]));
        t3 = fmaxf(t3, fmaxf(sA[r + 3], sB[r + 3]));
      }
      float tmax = fmaxf(fmaxf(t0, t1), fmaxf(t2, t3));
      tmax = fmaxf(tmax, __shfl_xor(tmax, 32));
      if (__any(tmax - m_run > 11.5f)) {     // defer-max
        float m_new = fmaxf(m_run, tmax);
        float sc = exp2_hw(m_run - m_new);
        l_run *= sc;
#pragma unroll
        for (int r = 0; r < 16; ++r) { o0[r] *= sc; o1[r] *= sc; }
        m_run = m_new;
      }
      float r0 = 0.f, r1 = 0.f, r2 = 0.f, r3 = 0.f;
#pragma unroll
      for (int r = 0; r < 16; r += 4) {
        sA[r] = exp2_hw(sA[r] - m_run);         r0 += sA[r];
        sA[r + 1] = exp2_hw(sA[r + 1] - m_run); r1 += sA[r + 1];
        sA[r + 2] = exp2_hw(sA[r + 2] - m_run); r2 += sA[r + 2];
        sA[r + 3] = exp2_hw(sA[r + 3] - m_run); r3 += sA[r + 3];
      }
#pragma unroll
      for (int r = 0; r < 16; r += 4) {
        sB[r] = exp2_hw(sB[r] - m_run);         r0 += sB[r];
        sB[r + 1] = exp2_hw(sB[r + 1] - m_run); r1 += sB[r + 1];
        sB[r + 2] = exp2_hw(sB[r + 2] - m_run); r2 += sB[r + 2];
        sB[r + 3] = exp2_hw(sB[r + 3] - m_run); r3 += sB[r + 3];
      }
      float rs = (r0 + r1) + (r2 + r3);
      rs += __shfl_xor(rs, 32);
      l_run += rs;
      // ---- pack P^T to bf16 fragments ----
      unsigned int pk[16];
#pragma unroll
      for (int ii = 0; ii < 8; ++ii) pk[ii]     = cvtpk_bf16(sA[2 * ii], sA[2 * ii + 1]);
#pragma unroll
      for (int ii = 0; ii < 8; ++ii) pk[8 + ii] = cvtpk_bf16(sB[2 * ii], sB[2 * ii + 1]);
      __builtin_amdgcn_s_setprio(1);
#pragma unroll
      for (int ks = 0; ks < 4; ++ks) {
        unsigned int A0 = pk[ks * 4 + 0], A1 = pk[ks * 4 + 1];
        unsigned int B0 = pk[ks * 4 + 2], B1 = pk[ks * 4 + 3];
        unsigned int xA0 = __shfl_xor(A0, 32), xA1 = __shfl_xor(A1, 32);
        unsigned int xB0 = __shfl_xor(B0, 32), xB1 = __shfl_xor(B1, 32);
        u32x4 uu;
        uu[0] = hi ? xB0 : A0;
        uu[1] = hi ? xB1 : A1;
        uu[2] = hi ? B0 : xA0;
        uu[3] = hi ? B1 : xA1;
        bf16x8 pf = __builtin_bit_cast(bf16x8, uu);
        const int cb = ((ks * 32 + hi * 16) ^ swz) >> 1;
        bf16x8 v0 = *(const bf16x8*)(vb + lq * 64 + cb);          // V^T rows d=lq
        bf16x8 v1 = *(const bf16x8*)(vb + (32 + lq) * 64 + cb);   // rows d=32+lq
        o0 = mfma32(v0, pf, o0);
        o1 = mfma32(v1, pf, o1);
      }
      __builtin_amdgcn_s_setprio(0);
    }
    __builtin_amdgcn_s_barrier();
  }
#undef STAGE

  const float inv = 1.0f / l_run;
  unsigned short* op = attn + ((size_t)q * B_DIM + b) * E_DIM + h * DH;
#pragma unroll
  for (int g = 0; g < 4; ++g) {
    u16x4 w0, w1;
#pragma unroll
    for (int jj = 0; jj < 4; ++jj) {
      w0[jj] = f2bf(o0[g * 4 + jj] * inv);
      w1[jj] = f2bf(o1[g * 4 + jj] * inv);
    }
    int d = 8 * g + 4 * hi;
    *(u16x4*)(op + d) = w0;
    *(u16x4*)(op + 32 + d) = w1;
  }
}

// ---------------- GEMM2: out = attn @ out_w^T + out_b (f32 out) ----------------
__global__ __launch_bounds__(256) void gemm_out(
    const unsigned short* __restrict__ A, const unsigned short* __restrict__ W,
    const float* __restrict__ bias, float* __restrict__ out) {
  __shared__ unsigned short lA[4096], lB[4096];
  f32x4 acc[4][4];
  const f32x4 z4 = {0.f, 0.f, 0.f, 0.f};
#pragma unroll
  for (int i = 0; i < 4; ++i)
#pragma unroll
    for (int j = 0; j < 4; ++j) acc[i][j] = z4;
  const int m0 = blockIdx.x * 128, n0 = blockIdx.y * 128;
  gemm_mainloop(A, W, 1024, m0, n0, lA, lB, acc);

  const int lane = threadIdx.x & 63, wave = threadIdx.x >> 6;
  const int lr = lane & 15, lg = lane >> 4;
  const int wr = wave >> 1, wc = wave & 1;
#pragma unroll
  for (int mi = 0; mi < 4; ++mi)
#pragma unroll
    for (int ni = 0; ni < 4; ++ni)
#pragma unroll
      for (int j = 0; j < 4; ++j) {
        int m = m0 + wr * 64 + mi * 16 + lg * 4 + j;
        int f = n0 + wc * 64 + ni * 16 + lr;
        out[(size_t)m * E_DIM + f] = acc[mi][ni][j] + bias[f];
      }
}

extern "C" void kernel_launch(void* const* d_in, const int* in_sizes, int n_in,
                              void* d_out, int out_size, void* d_ws, size_t ws_size,
                              hipStream_t stream) {
  const float* query = (const float*)d_in[0];
  const float* qkv_w = (const float*)d_in[1];
  const float* qkv_b = (const float*)d_in[2];
  const float* out_w = (const float*)d_in[3];
  const float* out_b = (const float*)d_in[4];
  float* out = (float*)d_out;

  char* ws = (char*)d_ws;
  unsigned short* Abf  = (unsigned short*)(ws);
  unsigned short* Wbf  = (unsigned short*)(ws + (size_t)(16u << 20));
  unsigned short* OWbf = (unsigned short*)(ws + (size_t)(22u << 20));
  unsigned short* Qh   = (unsigned short*)(ws + (size_t)(24u << 20));
  unsigned short* Kh   = (unsigned short*)(ws + (size_t)(40u << 20));
  unsigned short* Vh   = (unsigned short*)(ws + (size_t)(56u << 20));
  unsigned short* Vt   = (unsigned short*)(ws + (size_t)(72u << 20));
  unsigned short* attn = Abf;  // alias: query-bf16 dead after gemm_qkv

  cast_f32_to_bf16<<<8192, 256, 0, stream>>>(query, Abf, 8388608 / 4);
  cast_f32_to_bf16<<<3072, 256, 0, stream>>>(qkv_w, Wbf, 3145728 / 4);
  cast_f32_to_bf16<<<1024, 256, 0, stream>>>(out_w, OWbf, 1048576 / 4);
  gemm_qkv<<<dim3(64, 24), 256, 0, stream>>>(Abf, Wbf, qkv_b, Qh, Kh, Vh);
  transpose_v<<<dim3(128, 16), 256, 0, stream>>>(Vh, Vt);
  flash_attn6<<<1024, 256, 0, stream>>>(Qh, Kh, Vt, attn);
  gemm_out<<<dim3(64, 8), 256, 0, stream>>>(attn, OWbf, out_b, out);
}